// Round 1
// baseline (49.928 us; speedup 1.0000x reference)
//
#include <hip/hip_runtime.h>
#include <stdint.h>
#include <math.h>

#define EMBED 1024
#define NE 8
#define TPB_TOK 64   // tokens per block in phase 1 / phase 3

// ---------------------------------------------------------------------------
// Phase 1: logits (x @ W^T + b), softmax-free top-2 + renormalized weights,
//          per-block (64-token) histograms of (rank, expert) assignments.
// Block: 256 threads = 4 waves; each wave computes 4 tokens per iteration
// (W staged in LDS and reused across the 4 tokens).
// ---------------------------------------------------------------------------
__global__ __launch_bounds__(256) void router_phase1(
    const float* __restrict__ x, const float* __restrict__ W,
    const float* __restrict__ bias,
    uint32_t* __restrict__ idx_out, float2* __restrict__ w_out,
    int* __restrict__ hist)
{
    __shared__ float Wl[NE * EMBED];   // 32 KB
    __shared__ float bl[NE];
    __shared__ int   hl[16];
    const int tid = threadIdx.x;

    // stage W into LDS (2048 float4, 8 per thread), bias, zero histogram
    {
        const float4* Wg = (const float4*)W;
        float4*       Ws = (float4*)Wl;
        #pragma unroll
        for (int i = 0; i < (NE * EMBED / 4) / 256; ++i)
            Ws[tid + i * 256] = Wg[tid + i * 256];
    }
    if (tid < NE) bl[tid] = bias[tid];
    if (tid < 16) hl[tid] = 0;
    __syncthreads();

    const int wave  = tid >> 6;
    const int lane  = tid & 63;
    const int tbase = blockIdx.x * TPB_TOK;

    for (int it = 0; it < TPB_TOK / 16; ++it) {
        const int t0 = tbase + it * 16 + wave * 4;   // this wave's 4 tokens

        // load x fragments: lane covers channels {j*256 + lane*4 .. +3}
        float4 xa[4][4];
        #pragma unroll
        for (int tt = 0; tt < 4; ++tt) {
            const float* xp = x + (size_t)(t0 + tt) * EMBED + (lane << 2);
            #pragma unroll
            for (int j = 0; j < 4; ++j)
                xa[tt][j] = *(const float4*)(xp + j * 256);
        }

        float acc[4][NE];
        #pragma unroll
        for (int tt = 0; tt < 4; ++tt)
            #pragma unroll
            for (int e = 0; e < NE; ++e) acc[tt][e] = 0.0f;

        #pragma unroll
        for (int e = 0; e < NE; ++e) {
            #pragma unroll
            for (int j = 0; j < 4; ++j) {
                float4 wv = *(const float4*)(Wl + e * EMBED + j * 256 + (lane << 2));
                #pragma unroll
                for (int tt = 0; tt < 4; ++tt) {
                    acc[tt][e] = fmaf(xa[tt][j].x, wv.x, acc[tt][e]);
                    acc[tt][e] = fmaf(xa[tt][j].y, wv.y, acc[tt][e]);
                    acc[tt][e] = fmaf(xa[tt][j].z, wv.z, acc[tt][e]);
                    acc[tt][e] = fmaf(xa[tt][j].w, wv.w, acc[tt][e]);
                }
            }
        }

        // full-wave butterfly reduction: all lanes end with the 32 totals
        #pragma unroll
        for (int off = 32; off > 0; off >>= 1) {
            #pragma unroll
            for (int tt = 0; tt < 4; ++tt)
                #pragma unroll
                for (int e = 0; e < NE; ++e)
                    acc[tt][e] += __shfl_xor(acc[tt][e], off, 64);
        }

        // lane tt finalizes token t0+tt (top-2, weights, histogram)
        #pragma unroll
        for (int tt = 0; tt < 4; ++tt) {
            if (lane == tt) {
                float l[NE];
                #pragma unroll
                for (int e = 0; e < NE; ++e) l[e] = acc[tt][e] + bl[e];
                int i0 = 0; float v0 = l[0];
                #pragma unroll
                for (int e = 1; e < NE; ++e)
                    if (l[e] > v0) { v0 = l[e]; i0 = e; }
                float v1 = -3.4e38f; int i1 = 0;
                #pragma unroll
                for (int e = 0; e < NE; ++e)
                    if (e != i0 && l[e] > v1) { v1 = l[e]; i1 = e; }
                // renormalized top-2 softmax weights: denominator cancels
                float r  = expf(v1 - v0);
                float s  = 1.0f + r;
                float w0 = 1.0f / s;
                float w1 = r / s;
                const int t = t0 + tt;
                idx_out[t] = (uint32_t)i0 | ((uint32_t)i1 << 8);
                w_out[t]   = make_float2(w0, w1);
                atomicAdd(&hl[i0], 1);        // rank-0 category
                atomicAdd(&hl[8 + i1], 1);    // rank-1 category
            }
        }
    }

    __syncthreads();
    if (tid < 16) hist[blockIdx.x * 16 + tid] = hl[tid];
}

// ---------------------------------------------------------------------------
// Phase 2: exclusive scan of per-block histograms.
// 16 waves (1024 threads); wave w scans category w across nblk blocks.
// nblk/64 entries per lane; lane-local prefix + shfl_up wave scan.
// ---------------------------------------------------------------------------
__global__ __launch_bounds__(1024) void router_scan(
    const int* __restrict__ hist, int* __restrict__ offs, int nblk)
{
    const int cat  = threadIdx.x >> 6;   // 0..15
    const int lane = threadIdx.x & 63;
    const int epl  = nblk >> 6;          // entries per lane (512/64 = 8)

    int v[8];
    int run = 0;
    int ex[8];
    #pragma unroll
    for (int i = 0; i < 8; ++i) {
        int b = lane * epl + i;
        v[i]  = (i < epl) ? hist[b * 16 + cat] : 0;
        ex[i] = run;
        run  += v[i];
    }
    // wave-wide inclusive scan of per-lane totals
    int scan = run;
    #pragma unroll
    for (int off = 1; off < 64; off <<= 1) {
        int n = __shfl_up(scan, off, 64);
        if (lane >= off) scan += n;
    }
    int excl = scan - run;   // exclusive prefix across lanes
    #pragma unroll
    for (int i = 0; i < 8; ++i) {
        if (i < epl) {
            int b = lane * epl + i;
            offs[b * 16 + cat] = excl + ex[i];
        }
    }
}

// ---------------------------------------------------------------------------
// Phase 3: per-token position-in-expert via ballot/popcount + block offset,
//          capacity check, dispatch/combine write-out.
// One wave per 64 tokens.
// ---------------------------------------------------------------------------
__global__ __launch_bounds__(64) void router_finalize(
    const uint32_t* __restrict__ idx_in, const float2* __restrict__ w_in,
    const int* __restrict__ offs, float* __restrict__ out,
    int tokens, int capacity)
{
    const int blk  = blockIdx.x;
    const int lane = threadIdx.x;
    const int t    = blk * 64 + lane;

    const uint32_t pk = idx_in[t];
    const int e0 = pk & 0xff;
    const int e1 = (pk >> 8) & 0xff;
    const float2 w = w_in[t];

    const unsigned long long below = (1ull << lane) - 1ull;
    int cnt0 = 0, cnt1 = 0;
    #pragma unroll
    for (int e = 0; e < NE; ++e) {
        unsigned long long m0 = __ballot(e0 == e);
        if (e0 == e) cnt0 = __popcll(m0 & below);
        unsigned long long m1 = __ballot(e1 == e);
        if (e1 == e) cnt1 = __popcll(m1 & below);
    }

    const int pos0 = offs[blk * 16 + e0] + cnt0;
    const int pos1 = offs[blk * 16 + 8 + e1] + cnt1;
    const bool a0 = pos0 < capacity;
    const bool a1 = pos1 < capacity;

    const float sw  = (a0 ? w.x : 0.0f) + (a1 ? w.y : 0.0f);
    const float inv = 1.0f / fmaxf(sw, 1e-6f);

    float dv[NE], cv[NE];
    #pragma unroll
    for (int e = 0; e < NE; ++e) {
        const bool h0 = a0 && (e0 == e);
        const bool h1 = a1 && (e1 == e);
        dv[e] = (h0 || h1) ? 1.0f : 0.0f;
        cv[e] = h0 ? (w.x * inv) : (h1 ? (w.y * inv) : 0.0f);
    }

    float4* dp = (float4*)(out + (size_t)t * 8);
    dp[0] = make_float4(dv[0], dv[1], dv[2], dv[3]);
    dp[1] = make_float4(dv[4], dv[5], dv[6], dv[7]);
    float4* cp = (float4*)(out + (size_t)tokens * 8 + (size_t)t * 8);
    cp[0] = make_float4(cv[0], cv[1], cv[2], cv[3]);
    cp[1] = make_float4(cv[4], cv[5], cv[6], cv[7]);
}

// ---------------------------------------------------------------------------
extern "C" void kernel_launch(void* const* d_in, const int* in_sizes, int n_in,
                              void* d_out, int out_size, void* d_ws, size_t ws_size,
                              hipStream_t stream)
{
    const float* x = (const float*)d_in[0];
    const float* W = (const float*)d_in[1];
    const float* b = (const float*)d_in[2];
    float* out = (float*)d_out;

    const int tokens = in_sizes[0] / EMBED;           // 32768
    const int nblk   = tokens / TPB_TOK;              // 512
    const int capacity = (int)ceil(1.25 * (double)tokens * 2.0 / 8.0);  // 10240

    uint32_t* idxbuf = (uint32_t*)d_ws;
    float2*   wbuf   = (float2*)((char*)d_ws + (size_t)tokens * 4);
    int*      hist   = (int*)((char*)d_ws + (size_t)tokens * 12);
    int*      offs   = hist + nblk * 16;

    router_phase1  <<<nblk, 256, 0, stream>>>(x, W, b, idxbuf, wbuf, hist);
    router_scan    <<<1, 1024, 0, stream>>>(hist, offs, nblk);
    router_finalize<<<nblk, 64, 0, stream>>>(idxbuf, wbuf, offs, out, tokens, capacity);
}

// Round 3
// 46.482 us; speedup vs baseline: 1.0741x; 1.0741x over previous
//
#include <hip/hip_runtime.h>
#include <stdint.h>
#include <math.h>

#define EMBED 1024
#define NE 8
#define TPB_TOK 64   // tokens per phase-1 block / per finalize wave

// ---------------------------------------------------------------------------
// Phase 1: logits (x @ W^T + b), top-2 + renormalized weights (softmax
// denominator cancels), per-block (64-token) histograms of (rank, expert).
// 256 threads = 4 waves; each wave does 4 tokens/iter, x double-buffered
// so the next iteration's 16 KB is in flight during compute.
// ---------------------------------------------------------------------------
__global__ __launch_bounds__(256) void router_phase1(
    const float* __restrict__ x, const float* __restrict__ W,
    const float* __restrict__ bias,
    uint32_t* __restrict__ idx_out, float2* __restrict__ w_out,
    int* __restrict__ hist)
{
    __shared__ float Wl[NE * EMBED];   // 32 KB
    __shared__ float bl[NE];
    __shared__ int   hl[16];
    const int tid = threadIdx.x;

    {
        const float4* Wg = (const float4*)W;
        float4*       Ws = (float4*)Wl;
        #pragma unroll
        for (int i = 0; i < (NE * EMBED / 4) / 256; ++i)
            Ws[tid + i * 256] = Wg[tid + i * 256];
    }
    if (tid < NE) bl[tid] = bias[tid];
    if (tid < 16) hl[tid] = 0;
    __syncthreads();

    const int wave  = tid >> 6;
    const int lane  = tid & 63;
    const int tbase = blockIdx.x * TPB_TOK;

    float4 xa[2][4][4];   // [buf][token][chunk] — statically indexed (unrolled)

    // prologue: load iteration 0
    #pragma unroll
    for (int tt = 0; tt < 4; ++tt) {
        const float* xp = x + (size_t)(tbase + wave * 4 + tt) * EMBED + (lane << 2);
        #pragma unroll
        for (int j = 0; j < 4; ++j)
            xa[0][tt][j] = *(const float4*)(xp + j * 256);
    }

    #pragma unroll
    for (int it = 0; it < TPB_TOK / 16; ++it) {
        const int buf = it & 1;

        // prefetch next iteration (always in-bounds: it+1 <= 3 within block)
        if (it < TPB_TOK / 16 - 1) {
            const int tn = tbase + (it + 1) * 16 + wave * 4;
            #pragma unroll
            for (int tt = 0; tt < 4; ++tt) {
                const float* xp = x + (size_t)(tn + tt) * EMBED + (lane << 2);
                #pragma unroll
                for (int j = 0; j < 4; ++j)
                    xa[buf ^ 1][tt][j] = *(const float4*)(xp + j * 256);
            }
        }

        float acc[4][NE];
        #pragma unroll
        for (int tt = 0; tt < 4; ++tt)
            #pragma unroll
            for (int e = 0; e < NE; ++e) acc[tt][e] = 0.0f;

        #pragma unroll
        for (int e = 0; e < NE; ++e) {
            #pragma unroll
            for (int j = 0; j < 4; ++j) {
                float4 wv = *(const float4*)(Wl + e * EMBED + j * 256 + (lane << 2));
                #pragma unroll
                for (int tt = 0; tt < 4; ++tt) {
                    acc[tt][e] = fmaf(xa[buf][tt][j].x, wv.x, acc[tt][e]);
                    acc[tt][e] = fmaf(xa[buf][tt][j].y, wv.y, acc[tt][e]);
                    acc[tt][e] = fmaf(xa[buf][tt][j].z, wv.z, acc[tt][e]);
                    acc[tt][e] = fmaf(xa[buf][tt][j].w, wv.w, acc[tt][e]);
                }
            }
        }

        // full-wave butterfly: all lanes end with the 32 totals
        #pragma unroll
        for (int off = 32; off > 0; off >>= 1) {
            #pragma unroll
            for (int tt = 0; tt < 4; ++tt)
                #pragma unroll
                for (int e = 0; e < NE; ++e)
                    acc[tt][e] += __shfl_xor(acc[tt][e], off, 64);
        }

        #pragma unroll
        for (int tt = 0; tt < 4; ++tt) {
            if (lane == tt) {
                float l[NE];
                #pragma unroll
                for (int e = 0; e < NE; ++e) l[e] = acc[tt][e] + bl[e];
                int i0 = 0; float v0 = l[0];
                #pragma unroll
                for (int e = 1; e < NE; ++e)
                    if (l[e] > v0) { v0 = l[e]; i0 = e; }
                float v1 = -3.4e38f; int i1 = 0;
                #pragma unroll
                for (int e = 0; e < NE; ++e)
                    if (e != i0 && l[e] > v1) { v1 = l[e]; i1 = e; }
                float r  = expf(v1 - v0);
                float s  = 1.0f + r;
                const int t = tbase + it * 16 + wave * 4 + tt;
                idx_out[t] = (uint32_t)i0 | ((uint32_t)i1 << 8);
                w_out[t]   = make_float2(1.0f / s, r / s);
                atomicAdd(&hl[i0], 1);
                atomicAdd(&hl[8 + i1], 1);
            }
        }
    }

    __syncthreads();
    if (tid < 16) hist[blockIdx.x * 16 + tid] = hl[tid];
}

// ---------------------------------------------------------------------------
// Phase 2 (fused scan + finalize): 256 threads = 4 waves; wave w owns
// token-group g = blk*4 + w. Lane layout for the prefix: cat = lane&15,
// chunk = lane>>4; sum hist[gg*16+cat] over gg<g (4-way chunked), reduce
// chunks with shfl_xor, then value-indexed __shfl lookup — no LDS needed.
// ---------------------------------------------------------------------------
__global__ __launch_bounds__(256) void router_finalize(
    const uint32_t* __restrict__ idx_in, const float2* __restrict__ w_in,
    const int* __restrict__ hist, float* __restrict__ out,
    int tokens, int capacity)
{
    const int wave = threadIdx.x >> 6;
    const int lane = threadIdx.x & 63;
    const int g    = blockIdx.x * 4 + wave;     // 64-token group id

    // exclusive prefix over preceding groups for all 16 (rank,expert) cats
    const int cat   = lane & 15;
    const int chunk = lane >> 4;
    int s = 0;
    #pragma unroll 8
    for (int gg = chunk; gg < g; gg += 4) s += hist[gg * 16 + cat];
    s += __shfl_xor(s, 16, 64);
    s += __shfl_xor(s, 32, 64);   // lane (cat + 16k) holds prefix for cat

    const int t = g * 64 + lane;
    const uint32_t pk = idx_in[t];
    const int e0 = pk & 0xff;
    const int e1 = (pk >> 8) & 0xff;
    const float2 w = w_in[t];

    // within-group ordered position via ballot/popcount
    const unsigned long long below = (1ull << lane) - 1ull;
    int cnt0 = 0, cnt1 = 0;
    #pragma unroll
    for (int e = 0; e < NE; ++e) {
        unsigned long long m0 = __ballot(e0 == e);
        if (e0 == e) cnt0 = __popcll(m0 & below);
        unsigned long long m1 = __ballot(e1 == e);
        if (e1 == e) cnt1 = __popcll(m1 & below);
    }

    const int pos0 = __shfl(s, e0, 64) + cnt0;       // lane e0 holds cat e0
    const int pos1 = __shfl(s, 8 + e1, 64) + cnt1;   // lane 8+e1 holds cat 8+e1
    const bool a0 = pos0 < capacity;
    const bool a1 = pos1 < capacity;

    const float sw  = (a0 ? w.x : 0.0f) + (a1 ? w.y : 0.0f);
    const float inv = 1.0f / fmaxf(sw, 1e-6f);

    float dv[NE], cv[NE];
    #pragma unroll
    for (int e = 0; e < NE; ++e) {
        const bool h0 = a0 && (e0 == e);
        const bool h1 = a1 && (e1 == e);
        dv[e] = (h0 || h1) ? 1.0f : 0.0f;
        cv[e] = h0 ? (w.x * inv) : (h1 ? (w.y * inv) : 0.0f);
    }

    float4* dp = (float4*)(out + (size_t)t * 8);
    dp[0] = make_float4(dv[0], dv[1], dv[2], dv[3]);
    dp[1] = make_float4(dv[4], dv[5], dv[6], dv[7]);
    float4* cp = (float4*)(out + (size_t)tokens * 8 + (size_t)t * 8);
    cp[0] = make_float4(cv[0], cv[1], cv[2], cv[3]);
    cp[1] = make_float4(cv[4], cv[5], cv[6], cv[7]);
}

// ---------------------------------------------------------------------------
extern "C" void kernel_launch(void* const* d_in, const int* in_sizes, int n_in,
                              void* d_out, int out_size, void* d_ws, size_t ws_size,
                              hipStream_t stream)
{
    const float* x = (const float*)d_in[0];
    const float* W = (const float*)d_in[1];
    const float* b = (const float*)d_in[2];
    float* out = (float*)d_out;

    const int tokens   = in_sizes[0] / EMBED;                           // 32768
    const int nblk     = tokens / TPB_TOK;                              // 512
    const int capacity = (int)ceil(1.25 * (double)tokens * 2.0 / 8.0);  // 10240

    uint32_t* idxbuf = (uint32_t*)d_ws;
    float2*   wbuf   = (float2*)((char*)d_ws + (size_t)tokens * 4);
    int*      hist   = (int*)((char*)d_ws + (size_t)tokens * 12);

    router_phase1  <<<nblk, 256, 0, stream>>>(x, W, b, idxbuf, wbuf, hist);
    router_finalize<<<nblk / 4, 256, 0, stream>>>(idxbuf, wbuf, hist, out,
                                                  tokens, capacity);
}